// Round 1
// baseline (737.267 us; speedup 1.0000x reference)
//
#include <hip/hip_runtime.h>
#include <stdint.h>
#include <math.h>

typedef float f4 __attribute__((ext_vector_type(4)));

// ---------------- Threefry-2x32 (exact JAX replication) ----------------
static __device__ __forceinline__ uint32_t rotl32(uint32_t x, int r) {
    return (x << r) | (x >> (32 - r));
}

static __device__ __forceinline__ void tf2x32(uint32_t k0, uint32_t k1,
                                              uint32_t& x0, uint32_t& x1) {
    uint32_t ks2 = k0 ^ k1 ^ 0x1BD11BDAu;
    x0 += k0; x1 += k1;
#define TFR(r) { x0 += x1; x1 = rotl32(x1, r); x1 ^= x0; }
    TFR(13) TFR(15) TFR(26) TFR(6)
    x0 += k1;  x1 += ks2 + 1u;
    TFR(17) TFR(29) TFR(16) TFR(24)
    x0 += ks2; x1 += k0 + 2u;
    TFR(13) TFR(15) TFR(26) TFR(6)
    x0 += k0;  x1 += k1 + 3u;
    TFR(17) TFR(29) TFR(16) TFR(24)
    x0 += k1;  x1 += ks2 + 4u;
    TFR(13) TFR(15) TFR(26) TFR(6)
    x0 += ks2; x1 += k0 + 5u;
#undef TFR
}

// jax.random.split(key(42), 3): threefry_2x32((0,42), iota(6)) reshaped (3,2).
// out = [a0,a1,a2,b0,b1,b2] where (a_i,b_i) = cipher(i, i+3)
// k1=(a0,a1)  k2=(a2,b0)  k3=(b1,b2)
struct SubKeys { uint32_t k1a, k1b, k2a, k2b, k3a, k3b; };

static __device__ __forceinline__ SubKeys derive_keys() {
    uint32_t a0 = 0, b0 = 3; tf2x32(0u, 42u, a0, b0);
    uint32_t a1 = 1, b1 = 4; tf2x32(0u, 42u, a1, b1);
    uint32_t a2 = 2, b2 = 5; tf2x32(0u, 42u, a2, b2);
    SubKeys s; s.k1a = a0; s.k1b = a1; s.k2a = a2; s.k2b = b0; s.k3a = b1; s.k3b = b2;
    return s;
}

static __device__ __forceinline__ float bits_to_unit_float(uint32_t b) {
    return __uint_as_float((b >> 9) | 0x3f800000u) - 1.0f;
}

// ---------------- shared kernels ----------------
__global__ void k_seed(const int* __restrict__ seeds, int n_seeds,
                       unsigned char* __restrict__ seedm) {
    int i = blockIdx.x * blockDim.x + threadIdx.x;
    if (i < n_seeds) seedm[seeds[i]] = 1;
}

__global__ void k_edge1(const int* __restrict__ rows, const int* __restrict__ cols, int nnz,
                        const unsigned char* __restrict__ seedm,
                        unsigned char* __restrict__ keep, unsigned char* __restrict__ nxt) {
    int e = blockIdx.x * blockDim.x + threadIdx.x;
    if (e >= nnz) return;
    int r = rows[e], c = cols[e];
    bool inc = (seedm[r] | seedm[c]) != 0;
    keep[e] = inc ? 0 : 1;
    if (inc) { nxt[r] = 1; nxt[c] = 1; }   // same-value byte stores, race-safe
}

__global__ void k_edge2(const int* __restrict__ rows, const int* __restrict__ cols, int nnz,
                        const unsigned char* __restrict__ nxt,
                        unsigned char* __restrict__ keep) {
    int e = blockIdx.x * blockDim.x + threadIdx.x;
    if (e >= nnz) return;
    if (keep[e] && ((nxt[rows[e]] | nxt[cols[e]]) != 0)) keep[e] = 0;
}

__global__ void k_union(int n, const unsigned char* __restrict__ seedm,
                        const unsigned char* __restrict__ nxt,
                        unsigned char* __restrict__ mask) {
    int i = blockIdx.x * blockDim.x + threadIdx.x;
    if (i < n) mask[i] = (unsigned char)(seedm[i] | nxt[i]);
}

// samped = randint(k1,(samp_num,),0,N) with N=2^13 -> bits & (N-1).
__global__ void k_samp(int half, int modmask, unsigned char* __restrict__ mask) {
    int t = blockIdx.x * blockDim.x + threadIdx.x;
    if (t >= half) return;
    SubKeys sk = derive_keys();
    uint32_t x0 = (uint32_t)t, x1 = (uint32_t)(t + half);
    tf2x32(sk.k1a, sk.k1b, x0, x1);
    mask[x0 & (uint32_t)modmask] = 1;
    mask[x1 & (uint32_t)modmask] = 1;
}

// single-block scan: mask (n bytes, n<=8192) -> ascending mask_idx + tem_num
__global__ void __launch_bounds__(1024)
k_scan(int n, const unsigned char* __restrict__ mask,
       int* __restrict__ mask_idx, int* __restrict__ tem_num) {
    __shared__ int ssum[1024];
    int t = threadIdx.x;
    int per = n / 1024;           // 8 for n=8192
    int base = t * per;
    int loc[8];
    int s = 0;
    for (int j = 0; j < per; ++j) { loc[j] = mask[base + j]; s += loc[j]; }
    ssum[t] = s;
    __syncthreads();
    for (int off = 1; off < 1024; off <<= 1) {
        int v = (t >= off) ? ssum[t - off] : 0;
        __syncthreads();
        ssum[t] += v;
        __syncthreads();
    }
    int excl = ssum[t] - s;
    for (int j = 0; j < per; ++j)
        if (loc[j]) mask_idx[excl++] = base + j;
    if (t == 1023) *tem_num = ssum[1023];
}

__global__ void k_deg(const int* __restrict__ rows, const int* __restrict__ cols, int nnz,
                      const unsigned char* __restrict__ keep,
                      const float* __restrict__ comp, float* __restrict__ deg, int n) {
    int e = blockIdx.x * blockDim.x + threadIdx.x;
    if (e >= nnz) return;
    if (keep[e]) {
        int r = rows[e], c = cols[e];
        atomicAdd(&deg[r], comp[(size_t)r * n + c]);
    }
}

__global__ void k_norm(int n, const float* __restrict__ deg, float* __restrict__ nrm) {
    int i = blockIdx.x * blockDim.x + threadIdx.x;
    if (i < n) nrm[i] = 1.0f / sqrtf(deg[i] + 1e-12f);
}

// ---------------- fast path: coverage bitmaps + dense fused write ----------------
// bit layout: row r, column c -> word r*(n/32) + (c>>5), bit (c&31)

__global__ void k_cov_encdec(const int* __restrict__ rows, const int* __restrict__ cols,
                             int nnz, int n, const unsigned char* __restrict__ keep,
                             unsigned int* __restrict__ encb, unsigned int* __restrict__ decb) {
    int e = blockIdx.x * blockDim.x + threadIdx.x;
    int wpr = n >> 5;
    if (e < nnz) {
        if (keep[e]) {
            int r = rows[e], c = cols[e];
            size_t w = (size_t)r * wpr + (c >> 5);
            unsigned int b = 1u << (c & 31);
            atomicOr(&encb[w], b);
            atomicOr(&decb[w], b);
        }
    } else if (e < nnz + n) {
        int i = e - nnz;
        atomicOr(&decb[(size_t)i * wpr + (i >> 5)], 1u << (i & 31));
    }
}

// tem pairs: u1=uniform(k2,(NNZ,)), u2=uniform(k3,(NNZ,));
// thread e<half covers positions e (word0) and e+half (word1).
__global__ void k_cov_tem(int half, int n, const int* __restrict__ mask_idx,
                          const int* __restrict__ tem_num,
                          unsigned int* __restrict__ decb) {
    int e = blockIdx.x * blockDim.x + threadIdx.x;
    if (e >= half) return;
    SubKeys sk = derive_keys();
    float tf = (float)(*tem_num);
    int wpr = n >> 5;
    uint32_t u1a = (uint32_t)e, u1b = (uint32_t)(e + half);
    tf2x32(sk.k2a, sk.k2b, u1a, u1b);
    uint32_t u2a = (uint32_t)e, u2b = (uint32_t)(e + half);
    tf2x32(sk.k3a, sk.k3b, u2a, u2b);
#pragma unroll
    for (int j = 0; j < 2; ++j) {
        uint32_t b1 = j ? u1b : u1a;
        uint32_t b2 = j ? u2b : u2a;
        float uu1 = bits_to_unit_float(b1);
        float uu2 = bits_to_unit_float(b2);
        int i1 = (int)(uu1 * tf);   // floor==trunc for nonneg, f32 RN mul == jnp
        int i2 = (int)(uu2 * tf);
        int r = mask_idx[i1];
        int c = mask_idx[i2];
        atomicOr(&decb[(size_t)r * wpr + (c >> 5)], 1u << (c & 31));
        atomicOr(&decb[(size_t)c * wpr + (r >> 5)], 1u << (r & 31));
    }
}

// one block per row; blockDim = n/32 (=256); each thread handles 8 float4 quads
// (strided so consecutive lanes store consecutive 16B -> fully coalesced 1KB/instr).
__global__ void k_dense(int n, const unsigned int* __restrict__ encb,
                        const unsigned int* __restrict__ decb,
                        const float* __restrict__ comp, const float* __restrict__ nrm,
                        float* __restrict__ enc, float* __restrict__ dec) {
    __shared__ unsigned int se[1024], sd[1024];
    int r = blockIdx.x;
    int t = threadIdx.x;
    int wpr = n >> 5;                    // == blockDim.x
    se[t] = encb[(size_t)r * wpr + t];
    sd[t] = decb[(size_t)r * wpr + t];
    __syncthreads();
    float nr = nrm[r];
    int sh = (t & 7) * 4;                // nibble within word, same for all q
    int wq = wpr >> 3;                   // words per quad-stripe
    int wbase = t >> 3;
    size_t rowo = (size_t)r * n;
    const f4* compv = (const f4*)(comp + rowo);
    const f4* nrmv  = (const f4*)nrm;
    f4* encv = (f4*)(enc + rowo);
    f4* decv = (f4*)(dec + rowo);
#pragma unroll
    for (int q = 0; q < 8; ++q) {        // n/(4*wpr) == 8 always
        int f = q * wpr + t;             // float4 index within row
        unsigned int ew = (se[q * wq + wbase] >> sh) & 0xFu;
        unsigned int dw = (sd[q * wq + wbase] >> sh) & 0xFu;
        f4 ev = {0.f, 0.f, 0.f, 0.f};
        f4 dv = {0.f, 0.f, 0.f, 0.f};
        if (ew | dw) {
            f4 cv = compv[f];
            f4 nv = nrmv[f];
            if (ew & 1u) ev.x = cv.x * nr * nv.x;
            if (ew & 2u) ev.y = cv.y * nr * nv.y;
            if (ew & 4u) ev.z = cv.z * nr * nv.z;
            if (ew & 8u) ev.w = cv.w * nr * nv.w;
            if (dw & 1u) dv.x = cv.x;
            if (dw & 2u) dv.y = cv.y;
            if (dw & 4u) dv.z = cv.z;
            if (dw & 8u) dv.w = cv.w;
        }
        __builtin_nontemporal_store(ev, &encv[f]);
        __builtin_nontemporal_store(dv, &decv[f]);
    }
}

// ---------------- fallback path (previous verified kernels) ----------------
__global__ void k_enc(const int* __restrict__ rows, const int* __restrict__ cols, int nnz,
                      const unsigned char* __restrict__ keep,
                      const float* __restrict__ comp, const float* __restrict__ nrm,
                      float* __restrict__ enc, int n) {
    int e = blockIdx.x * blockDim.x + threadIdx.x;
    if (e >= nnz) return;
    if (keep[e]) {
        int r = rows[e], c = cols[e];
        size_t o = (size_t)r * n + c;
        enc[o] = comp[o] * nrm[r] * nrm[c];
    }
}

__global__ void k_dec_base(const int* __restrict__ rows, const int* __restrict__ cols,
                           int nnz, int n, const unsigned char* __restrict__ keep,
                           const float* __restrict__ comp, float* __restrict__ dec) {
    int e = blockIdx.x * blockDim.x + threadIdx.x;
    if (e < nnz) {
        if (keep[e]) {
            size_t o = (size_t)rows[e] * n + cols[e];
            dec[o] = comp[o];
        }
    } else if (e < nnz + n) {
        int i = e - nnz;
        size_t o = (size_t)i * n + i;
        dec[o] = comp[o];
    }
}

__global__ void k_dec_tem(int half, int n, const int* __restrict__ mask_idx,
                          const int* __restrict__ tem_num,
                          const float* __restrict__ comp, float* __restrict__ dec) {
    int e = blockIdx.x * blockDim.x + threadIdx.x;
    if (e >= half) return;
    SubKeys sk = derive_keys();
    float tf = (float)(*tem_num);
    uint32_t u1a = (uint32_t)e, u1b = (uint32_t)(e + half);
    tf2x32(sk.k2a, sk.k2b, u1a, u1b);
    uint32_t u2a = (uint32_t)e, u2b = (uint32_t)(e + half);
    tf2x32(sk.k3a, sk.k3b, u2a, u2b);
#pragma unroll
    for (int j = 0; j < 2; ++j) {
        uint32_t b1 = j ? u1b : u1a;
        uint32_t b2 = j ? u2b : u2a;
        float uu1 = bits_to_unit_float(b1);
        float uu2 = bits_to_unit_float(b2);
        int i1 = (int)(uu1 * tf);
        int i2 = (int)(uu2 * tf);
        int r = mask_idx[i1];
        int c = mask_idx[i2];
        size_t o1 = (size_t)r * n + c;
        size_t o2 = (size_t)c * n + r;
        dec[o1] = comp[o1];
        dec[o2] = comp[o2];
    }
}

// ---------------- launch ----------------
extern "C" void kernel_launch(void* const* d_in, const int* in_sizes, int n_in,
                              void* d_out, int out_size, void* d_ws, size_t ws_size,
                              hipStream_t stream) {
    const int*   rows  = (const int*)d_in[0];
    const int*   cols  = (const int*)d_in[1];
    // d_in[2] = adj_values — unused by the forward
    const int*   seeds = (const int*)d_in[3];
    const float* comp  = (const float*)d_in[4];

    const int nnz     = in_sizes[0];
    const int n_seeds = in_sizes[3];
    const int n       = (int)(sqrt((double)in_sizes[4]) + 0.5);   // 8192

    float* enc = (float*)d_out;
    float* dec = enc + (size_t)n * n;

    // workspace layout (small region identical to previous verified kernel)
    char* ws = (char*)d_ws;
    float* deg            = (float*)(ws);
    float* nrm            = (float*)(ws + 4 * (size_t)n);
    int*   mask_idx       = (int*)  (ws + 8 * (size_t)n);
    int*   tem_num        = (int*)  (ws + 12 * (size_t)n + 256 - 256); // = ws + 12n
    unsigned char* seedm  = (unsigned char*)(ws + 12 * (size_t)n + 256);
    unsigned char* nxt    = seedm + n;
    unsigned char* mask   = nxt + n;
    unsigned char* keep   = mask + n;   // nnz bytes, fully written each call

    size_t small_end = 12 * (size_t)n + 256 + 3 * (size_t)n + (size_t)nnz;
    size_t bm_off    = (small_end + 255) & ~(size_t)255;
    size_t bm_bytes  = ((size_t)n * (size_t)n) / 8;   // 8 MB at n=8192
    bool fast = (ws_size >= bm_off + 2 * bm_bytes) && ((n & 1023) == 0) && (n >> 5) <= 1024;

    const int B = 256;
    int samp_num = (int)((double)n * 0.9);   // int(N*0.9) = 7372 (even)
    int shalf = samp_num / 2;
    int ehalf = nnz / 2;

    if (fast) {
        unsigned int* encb = (unsigned int*)(ws + bm_off);
        unsigned int* decb = (unsigned int*)(ws + bm_off + bm_bytes);

        // zero small region + both bitmaps in one shot (~17 MB); NO d_out memset.
        hipMemsetAsync(d_ws, 0, bm_off + 2 * bm_bytes, stream);

        k_seed <<<(n_seeds + B - 1) / B, B, 0, stream>>>(seeds, n_seeds, seedm);
        k_edge1<<<(nnz + B - 1) / B, B, 0, stream>>>(rows, cols, nnz, seedm, keep, nxt);
        k_edge2<<<(nnz + B - 1) / B, B, 0, stream>>>(rows, cols, nnz, nxt, keep);
        k_union<<<(n + B - 1) / B, B, 0, stream>>>(n, seedm, nxt, mask);
        k_samp <<<(shalf + B - 1) / B, B, 0, stream>>>(shalf, n - 1, mask);
        k_scan <<<1, 1024, 0, stream>>>(n, mask, mask_idx, tem_num);
        k_deg  <<<(nnz + B - 1) / B, B, 0, stream>>>(rows, cols, nnz, keep, comp, deg, n);
        k_norm <<<(n + B - 1) / B, B, 0, stream>>>(n, deg, nrm);

        k_cov_encdec<<<(nnz + n + B - 1) / B, B, 0, stream>>>(rows, cols, nnz, n, keep, encb, decb);
        k_cov_tem   <<<(ehalf + B - 1) / B, B, 0, stream>>>(ehalf, n, mask_idx, tem_num, decb);

        k_dense<<<n, n >> 5, 0, stream>>>(n, encb, decb, comp, nrm, enc, dec);
    } else {
        // previous verified path
        size_t zbytes = 12 * (size_t)n + 256 + 3 * (size_t)n;
        hipMemsetAsync(d_ws, 0, zbytes, stream);
        hipMemsetAsync(d_out, 0, (size_t)out_size * sizeof(float), stream);

        k_seed <<<(n_seeds + B - 1) / B, B, 0, stream>>>(seeds, n_seeds, seedm);
        k_edge1<<<(nnz + B - 1) / B, B, 0, stream>>>(rows, cols, nnz, seedm, keep, nxt);
        k_edge2<<<(nnz + B - 1) / B, B, 0, stream>>>(rows, cols, nnz, nxt, keep);
        k_union<<<(n + B - 1) / B, B, 0, stream>>>(n, seedm, nxt, mask);
        k_samp <<<(shalf + B - 1) / B, B, 0, stream>>>(shalf, n - 1, mask);
        k_scan <<<1, 1024, 0, stream>>>(n, mask, mask_idx, tem_num);
        k_deg  <<<(nnz + B - 1) / B, B, 0, stream>>>(rows, cols, nnz, keep, comp, deg, n);
        k_norm <<<(n + B - 1) / B, B, 0, stream>>>(n, deg, nrm);
        k_enc  <<<(nnz + B - 1) / B, B, 0, stream>>>(rows, cols, nnz, keep, comp, nrm, enc, n);
        k_dec_base<<<(nnz + n + B - 1) / B, B, 0, stream>>>(rows, cols, nnz, n, keep, comp, dec);
        k_dec_tem<<<(ehalf + B - 1) / B, B, 0, stream>>>(ehalf, n, mask_idx, tem_num, comp, dec);
    }
}